// Round 4
// baseline (90.457 us; speedup 1.0000x reference)
//
#include <hip/hip_runtime.h>
#include <hip/hip_bf16.h>
#include <hip/hip_fp16.h>
#include <stdint.h>

#define B_ROWS 2048
#define FEAT   2048
#define NK     128
#define ND     16
#define NCOL   2048   // NK*ND

#define BM 128
#define BN 128
#define BK 64

typedef __attribute__((ext_vector_type(4))) float    f32x4;
typedef __attribute__((ext_vector_type(8)))  _Float16 f16x8;
typedef __attribute__((ext_vector_type(4)))  _Float16 f16x4;
typedef __attribute__((ext_vector_type(2)))  _Float16 f16x2;
typedef __attribute__((ext_vector_type(4))) unsigned int u32x4;

__device__ __forceinline__ f16x8 habs8(f16x8 v) {
    u32x4 u = __builtin_bit_cast(u32x4, v);
    u.x &= 0x7fff7fffu; u.y &= 0x7fff7fffu; u.z &= 0x7fff7fffu; u.w &= 0x7fff7fffu;
    return __builtin_bit_cast(f16x8, u);
}

// ------------- Kernel 1: fused x-convert + W-transpose/convert (f16) ------
__global__ __launch_bounds__(256) void k_prep(const float* __restrict__ x,
                                              const float* __restrict__ W,
                                              _Float16* __restrict__ x_h,
                                              _Float16* __restrict__ Wt) {
    __shared__ float tile[32][33];
    int bb = blockIdx.x;
    if (bb < 4096) {
        int i = bb * 256 + threadIdx.x;
        float4 v = ((const float4*)x)[i];
        f16x4 o = { (_Float16)v.x, (_Float16)v.y, (_Float16)v.z, (_Float16)v.w };
        *(f16x4*)&x_h[(size_t)i * 4] = o;
    } else {
        bb -= 4096;
        int tid = threadIdx.x;
        int tx = tid & 31, ty = tid >> 5;   // 32 x 8
        int n0 = (bb & 63) * 32, k0 = (bb >> 6) * 32;
        #pragma unroll
        for (int i = 0; i < 4; ++i)
            tile[ty + i * 8][tx] = W[(size_t)(k0 + ty + i * 8) * NCOL + n0 + tx];
        __syncthreads();
        #pragma unroll
        for (int i = 0; i < 4; ++i)
            Wt[(size_t)(n0 + ty + i * 8) * FEAT + k0 + tx] = (_Float16)tile[tx][ty + i * 8];
    }
}

// ---------------- Kernel 2: f16 MFMA GEMM, split-K over grid.z ------------
// A row-major [M][K] f16, Bt row-major [N][K] f16; f16 partial C per slice.
__global__ __launch_bounds__(256) void k_gemm(const _Float16* __restrict__ A,
                                              const _Float16* __restrict__ Bt,
                                              _Float16* __restrict__ Cparts,
                                              int kt_per) {
    __shared__ __align__(16) unsigned short As[BM * BK];  // 16KB
    __shared__ __align__(16) unsigned short Bs[BN * BK];  // 16KB
    const int tid  = threadIdx.x;
    const int wave = tid >> 6;
    const int lane = tid & 63;
    const int bm = blockIdx.y, bn = blockIdx.x, z = blockIdx.z;
    _Float16* C = Cparts + (size_t)z * B_ROWS * NCOL;
    const int wm = (wave >> 1) * 64;
    const int wn = (wave & 1) * 64;

    const int srow  = lane >> 3;
    const int skcol = (lane & 7) * 8;

    f32x4 acc[4][4];
    #pragma unroll
    for (int i = 0; i < 4; ++i)
        #pragma unroll
        for (int j = 0; j < 4; ++j)
            acc[i][j] = (f32x4){0.f, 0.f, 0.f, 0.f};

    const int fr = lane & 15;
    const int fk = (lane >> 4) * 8;

    const int kt0 = z * kt_per;
    for (int kt = kt0; kt < kt0 + kt_per; ++kt) {
        const int k0 = kt * BK;
        __syncthreads();
        #pragma unroll
        for (int r = 0; r < 4; ++r) {
            const int mrow = wave * 32 + r * 8 + srow;
            const _Float16* ga = A  + (size_t)(bm * BM + mrow) * FEAT + k0 + skcol;
            const _Float16* gb = Bt + (size_t)(bn * BN + mrow) * FEAT + k0 + skcol;
            unsigned short* la = As + (wave * 4 + r) * 512;
            unsigned short* lb = Bs + (wave * 4 + r) * 512;
            __builtin_amdgcn_global_load_lds((const __attribute__((address_space(1))) uint32_t*)ga,
                                             (__attribute__((address_space(3))) uint32_t*)la, 16, 0, 0);
            __builtin_amdgcn_global_load_lds((const __attribute__((address_space(1))) uint32_t*)gb,
                                             (__attribute__((address_space(3))) uint32_t*)lb, 16, 0, 0);
        }
        __syncthreads();
        #pragma unroll
        for (int kk = 0; kk < BK; kk += 32) {
            f16x8 av[4], bv[4];
            #pragma unroll
            for (int t = 0; t < 4; ++t)
                av[t] = *(const f16x8*)&As[(wm + t * 16 + fr) * BK + kk + fk];
            #pragma unroll
            for (int t = 0; t < 4; ++t)
                bv[t] = *(const f16x8*)&Bs[(wn + t * 16 + fr) * BK + kk + fk];
            #pragma unroll
            for (int i = 0; i < 4; ++i)
                #pragma unroll
                for (int j = 0; j < 4; ++j)
                    acc[i][j] = __builtin_amdgcn_mfma_f32_16x16x32_f16(av[i], bv[j], acc[i][j], 0, 0, 0);
        }
    }

    // D layout: col = lane&15, row = (lane>>4)*4 + r
    const int crow0 = bm * BM + wm + (lane >> 4) * 4;
    const int ccol0 = bn * BN + wn + (lane & 15);
    #pragma unroll
    for (int i = 0; i < 4; ++i)
        #pragma unroll
        for (int j = 0; j < 4; ++j)
            #pragma unroll
            for (int r = 0; r < 4; ++r)
                C[(size_t)(crow0 + i * 16 + r) * NCOL + ccol0 + j * 16] = (_Float16)acc[i][j][r];
}

// ---------------- Kernel 3: pairwise L1 + exp (f16 packed) ----------------
// 256 threads = 2 rows x {2 j-halves x 64 lanes}. Thread owns outputs
// i = tl and tl+64 for its row, over j in [jh*64, jh*64+64). 1024 blocks
// x 4 waves = 4096 waves = 4/SIMD. vj = 2 ds_read_b128 per j, shared by
// both i's -> LDS-issue ~8x below R3; packed v_pk f16 math for the L1.
#define RPB 2
__global__ __launch_bounds__(256) void k_pairwise(const _Float16* __restrict__ Mp,
                                                  int nparts,
                                                  float* __restrict__ Os) {
    __shared__ _Float16 rows_l[RPB * NCOL];   // 8KB (summed partials)
    __shared__ float    part[RPB][2][NK];     // 4KB
    const int b0 = blockIdx.x * RPB;
    const int t  = threadIdx.x;
    const int r  = t >> 7;             // row within block (wave-uniform)
    const int jh = (t >> 6) & 1;       // j-half (wave-uniform)
    const int tl = t & 63;             // lane: owns i = tl and tl+64

    const size_t PART = (size_t)B_ROWS * NCOL;
    const size_t gbase = (size_t)b0 * NCOL;

    // Stage nparts-summed f16 rows into LDS (f16x8 chunks, packed adds)
    for (int idx = t; idx < RPB * NCOL / 8; idx += 256) {
        f16x8 v = *(const f16x8*)(Mp + gbase + (size_t)idx * 8);
        for (int z = 1; z < nparts; ++z)
            v = v + *(const f16x8*)(Mp + (size_t)z * PART + gbase + (size_t)idx * 8);
        *(f16x8*)&rows_l[idx * 8] = v;
    }
    __syncthreads();

    const _Float16* rowl = rows_l + r * NCOL;
    // Own fragments (identical LDS values as vj -> diagonal diff exactly 0)
    f16x8 maA = *(const f16x8*)&rowl[tl * ND];
    f16x8 maB = *(const f16x8*)&rowl[tl * ND + 8];
    f16x8 mbA = *(const f16x8*)&rowl[(tl + 64) * ND];
    f16x8 mbB = *(const f16x8*)&rowl[(tl + 64) * ND + 8];

    float acc0 = 0.f, acc1 = 0.f;
    const int j0 = jh * 64;
    for (int jj = 0; jj < 64; ++jj) {
        const int j = j0 + jj;
        f16x8 vA = *(const f16x8*)&rowl[j * ND];       // wave-uniform broadcast
        f16x8 vB = *(const f16x8*)&rowl[j * ND + 8];
        {
            f16x8 s8 = habs8(maA - vA) + habs8(maB - vB);
            f16x4 s4 = __builtin_shufflevector(s8, s8, 0, 1, 2, 3)
                     + __builtin_shufflevector(s8, s8, 4, 5, 6, 7);
            f16x2 s2 = __builtin_shufflevector(s4, s4, 0, 1)
                     + __builtin_shufflevector(s4, s4, 2, 3);
            float nrm = (float)s2[0] + (float)s2[1];
            acc0 += __expf(-nrm);
        }
        {
            f16x8 s8 = habs8(mbA - vA) + habs8(mbB - vB);
            f16x4 s4 = __builtin_shufflevector(s8, s8, 0, 1, 2, 3)
                     + __builtin_shufflevector(s8, s8, 4, 5, 6, 7);
            f16x2 s2 = __builtin_shufflevector(s4, s4, 0, 1)
                     + __builtin_shufflevector(s4, s4, 2, 3);
            float nrm = (float)s2[0] + (float)s2[1];
            acc1 += __expf(-nrm);
        }
    }
    part[r][jh][tl]      = acc0;
    part[r][jh][tl + 64] = acc1;
    __syncthreads();
    if (jh == 0) {
        const size_t row = (size_t)(b0 + r) * NK;
        Os[row + tl]      = part[r][0][tl]      + part[r][1][tl];
        Os[row + tl + 64] = part[r][0][tl + 64] + part[r][1][tl + 64];
    }
}

extern "C" void kernel_launch(void* const* d_in, const int* in_sizes, int n_in,
                              void* d_out, int out_size, void* d_ws, size_t ws_size,
                              hipStream_t stream) {
    const float* x = (const float*)d_in[0];
    const float* W = (const float*)d_in[1];
    float* Os = (float*)d_out;

    char* ws = (char*)d_ws;
    _Float16* x_h = (_Float16*)ws;                                  // 8MB
    _Float16* Wt  = (_Float16*)(ws + (size_t)8  * 1024 * 1024);     // 8MB
    _Float16* Mp  = (_Float16*)(ws + (size_t)16 * 1024 * 1024);     // 8MB x nsplit

    const size_t MB = (size_t)1024 * 1024;
    int nsplit = 1;
    if      (ws_size >= 48 * MB) nsplit = 4;   // 16 + 4*8 = 48MB
    else if (ws_size >= 32 * MB) nsplit = 2;

    k_prep<<<8192, 256, 0, stream>>>(x, W, x_h, Wt);

    dim3 gg(NCOL / BN, B_ROWS / BM, nsplit);  // 16 x 16 x nsplit
    k_gemm<<<gg, 256, 0, stream>>>(x_h, Wt, Mp, (FEAT / BK) / nsplit);

    k_pairwise<<<B_ROWS / RPB, 256, 0, stream>>>(Mp, nsplit, Os);
}

// Round 5
// 74.722 us; speedup vs baseline: 1.2106x; 1.2106x over previous
//
#include <hip/hip_runtime.h>
#include <hip/hip_bf16.h>
#include <hip/hip_fp16.h>
#include <stdint.h>

#define B_ROWS 2048
#define FEAT   2048
#define NK     128
#define ND     16
#define NCOL   2048   // NK*ND

#define BM 128
#define BN 128
#define BK 64

typedef __attribute__((ext_vector_type(4))) float    f32x4;
typedef __attribute__((ext_vector_type(8)))  _Float16 f16x8;
typedef __attribute__((ext_vector_type(4)))  _Float16 f16x4;
typedef __attribute__((ext_vector_type(2)))  _Float16 f16x2;

__device__ __forceinline__ f16x2 u2h(unsigned u) { return __builtin_bit_cast(f16x2, u); }
__device__ __forceinline__ f16x2 absdiff2(f16x2 a, f16x2 b) {
    f16x2 d = a - b;                       // v_pk_sub_f16
    unsigned u = __builtin_bit_cast(unsigned, d) & 0x7fff7fffu;  // v_and_b32 (abs both halves)
    return __builtin_bit_cast(f16x2, u);
}

// ------------- Kernel 1: fused x-convert + W-transpose/convert (f16) ------
__global__ __launch_bounds__(256) void k_prep(const float* __restrict__ x,
                                              const float* __restrict__ W,
                                              _Float16* __restrict__ x_h,
                                              _Float16* __restrict__ Wt) {
    __shared__ float tile[32][33];
    int bb = blockIdx.x;
    if (bb < 4096) {
        int i = bb * 256 + threadIdx.x;
        float4 v = ((const float4*)x)[i];
        f16x4 o = { (_Float16)v.x, (_Float16)v.y, (_Float16)v.z, (_Float16)v.w };
        *(f16x4*)&x_h[(size_t)i * 4] = o;
    } else {
        bb -= 4096;
        int tid = threadIdx.x;
        int tx = tid & 31, ty = tid >> 5;   // 32 x 8
        int n0 = (bb & 63) * 32, k0 = (bb >> 6) * 32;
        #pragma unroll
        for (int i = 0; i < 4; ++i)
            tile[ty + i * 8][tx] = W[(size_t)(k0 + ty + i * 8) * NCOL + n0 + tx];
        __syncthreads();
        #pragma unroll
        for (int i = 0; i < 4; ++i)
            Wt[(size_t)(n0 + ty + i * 8) * FEAT + k0 + tx] = (_Float16)tile[tx][ty + i * 8];
    }
}

// ---------------- Kernel 2: f16 MFMA GEMM, split-K over grid.z ------------
__global__ __launch_bounds__(256) void k_gemm(const _Float16* __restrict__ A,
                                              const _Float16* __restrict__ Bt,
                                              _Float16* __restrict__ Cparts,
                                              int kt_per) {
    __shared__ __align__(16) unsigned short As[BM * BK];  // 16KB
    __shared__ __align__(16) unsigned short Bs[BN * BK];  // 16KB
    const int tid  = threadIdx.x;
    const int wave = tid >> 6;
    const int lane = tid & 63;
    const int bm = blockIdx.y, bn = blockIdx.x, z = blockIdx.z;
    _Float16* C = Cparts + (size_t)z * B_ROWS * NCOL;
    const int wm = (wave >> 1) * 64;
    const int wn = (wave & 1) * 64;

    const int srow  = lane >> 3;
    const int skcol = (lane & 7) * 8;

    f32x4 acc[4][4];
    #pragma unroll
    for (int i = 0; i < 4; ++i)
        #pragma unroll
        for (int j = 0; j < 4; ++j)
            acc[i][j] = (f32x4){0.f, 0.f, 0.f, 0.f};

    const int fr = lane & 15;
    const int fk = (lane >> 4) * 8;

    const int kt0 = z * kt_per;
    for (int kt = kt0; kt < kt0 + kt_per; ++kt) {
        const int k0 = kt * BK;
        __syncthreads();
        #pragma unroll
        for (int r = 0; r < 4; ++r) {
            const int mrow = wave * 32 + r * 8 + srow;
            const _Float16* ga = A  + (size_t)(bm * BM + mrow) * FEAT + k0 + skcol;
            const _Float16* gb = Bt + (size_t)(bn * BN + mrow) * FEAT + k0 + skcol;
            unsigned short* la = As + (wave * 4 + r) * 512;
            unsigned short* lb = Bs + (wave * 4 + r) * 512;
            __builtin_amdgcn_global_load_lds((const __attribute__((address_space(1))) uint32_t*)ga,
                                             (__attribute__((address_space(3))) uint32_t*)la, 16, 0, 0);
            __builtin_amdgcn_global_load_lds((const __attribute__((address_space(1))) uint32_t*)gb,
                                             (__attribute__((address_space(3))) uint32_t*)lb, 16, 0, 0);
        }
        __syncthreads();
        #pragma unroll
        for (int kk = 0; kk < BK; kk += 32) {
            f16x8 av[4], bv[4];
            #pragma unroll
            for (int t = 0; t < 4; ++t)
                av[t] = *(const f16x8*)&As[(wm + t * 16 + fr) * BK + kk + fk];
            #pragma unroll
            for (int t = 0; t < 4; ++t)
                bv[t] = *(const f16x8*)&Bs[(wn + t * 16 + fr) * BK + kk + fk];
            #pragma unroll
            for (int i = 0; i < 4; ++i)
                #pragma unroll
                for (int j = 0; j < 4; ++j)
                    acc[i][j] = __builtin_amdgcn_mfma_f32_16x16x32_f16(av[i], bv[j], acc[i][j], 0, 0, 0);
        }
    }

    const int crow0 = bm * BM + wm + (lane >> 4) * 4;
    const int ccol0 = bn * BN + wn + (lane & 15);
    #pragma unroll
    for (int i = 0; i < 4; ++i)
        #pragma unroll
        for (int j = 0; j < 4; ++j)
            #pragma unroll
            for (int r = 0; r < 4; ++r)
                C[(size_t)(crow0 + i * 16 + r) * NCOL + ccol0 + j * 16] = (_Float16)acc[i][j][r];
}

// ---------------- Kernel 3: pairwise L1 + exp2 (clean packed-f16) ---------
// One batch row per block (2048 blocks, 8/CU -> 32 waves/CU). 256 threads:
// i = t&127 (output kernel), jh = t>>7 (j-half). Staged row pre-scaled by
// log2(e) so the inner loop is exp2(-sum|d|): per pair 8 pk_sub + 8 and +
// 7 pk_add + 1 add_f16 + 1 cvt + 1 exp + 1 acc, all named registers.
__global__ __launch_bounds__(256) void k_pairwise(const _Float16* __restrict__ Mp,
                                                  int nparts,
                                                  float* __restrict__ Os) {
    __shared__ _Float16 rowl[NCOL];        // 4KB
    __shared__ float    part[2][NK];       // 1KB
    const int b  = blockIdx.x;
    const int t  = threadIdx.x;
    const int i  = t & 127;
    const int jh = t >> 7;                 // wave-uniform (waves 0,1 / 2,3)

    const size_t PART  = (size_t)B_ROWS * NCOL;
    const size_t gbase = (size_t)b * NCOL;
    const f16x2 lg2e = { (_Float16)1.44269504f, (_Float16)1.44269504f };

    // Stage: each thread one f16x8 chunk; sum split-K partials; scale.
    {
        f16x8 v = *(const f16x8*)(Mp + gbase + (size_t)t * 8);
        for (int z = 1; z < nparts; ++z)
            v = v + *(const f16x8*)(Mp + (size_t)z * PART + gbase + (size_t)t * 8);
        f16x2 a0 = { v[0], v[1] }, a1 = { v[2], v[3] }, a2 = { v[4], v[5] }, a3 = { v[6], v[7] };
        a0 *= lg2e; a1 *= lg2e; a2 *= lg2e; a3 *= lg2e;
        uint4 w = { __builtin_bit_cast(unsigned, a0), __builtin_bit_cast(unsigned, a1),
                    __builtin_bit_cast(unsigned, a2), __builtin_bit_cast(unsigned, a3) };
        *(uint4*)&rowl[t * 8] = w;
    }
    __syncthreads();

    // Own row fragment: 8 named f16x2 regs (two b128 reads).
    const uint4 ua = *(const uint4*)&rowl[i * ND];
    const uint4 ub = *(const uint4*)&rowl[i * ND + 8];
    const f16x2 m0 = u2h(ua.x), m1 = u2h(ua.y), m2 = u2h(ua.z), m3 = u2h(ua.w);
    const f16x2 m4 = u2h(ub.x), m5 = u2h(ub.y), m6 = u2h(ub.z), m7 = u2h(ub.w);

    float acc0 = 0.f, acc1 = 0.f;
    const _Float16* jp = rowl + jh * 64 * ND;
    #pragma unroll 2
    for (int jj = 0; jj < 64; ++jj) {
        const uint4 va = *(const uint4*)(jp + jj * ND);      // wave-uniform broadcast
        const uint4 vb = *(const uint4*)(jp + jj * ND + 8);
        f16x2 s0 = absdiff2(m0, u2h(va.x)) + absdiff2(m1, u2h(va.y));
        f16x2 s1 = absdiff2(m2, u2h(va.z)) + absdiff2(m3, u2h(va.w));
        f16x2 s2 = absdiff2(m4, u2h(vb.x)) + absdiff2(m5, u2h(vb.y));
        f16x2 s3 = absdiff2(m6, u2h(vb.z)) + absdiff2(m7, u2h(vb.w));
        f16x2 s01 = s0 + s1, s23 = s2 + s3;
        f16x2 s = s01 + s23;
        _Float16 nh = s[0] + s[1];             // v_add_f16
        float nrm = (float)nh;                 // v_cvt_f32_f16
        if (jj & 1) acc1 += __builtin_amdgcn_exp2f(-nrm);
        else        acc0 += __builtin_amdgcn_exp2f(-nrm);
    }
    part[jh][i] = acc0 + acc1;
    __syncthreads();
    if (t < NK) Os[(size_t)b * NK + t] = part[0][t] + part[1][t];
}

extern "C" void kernel_launch(void* const* d_in, const int* in_sizes, int n_in,
                              void* d_out, int out_size, void* d_ws, size_t ws_size,
                              hipStream_t stream) {
    const float* x = (const float*)d_in[0];
    const float* W = (const float*)d_in[1];
    float* Os = (float*)d_out;

    char* ws = (char*)d_ws;
    _Float16* x_h = (_Float16*)ws;                                  // 8MB
    _Float16* Wt  = (_Float16*)(ws + (size_t)8  * 1024 * 1024);     // 8MB
    _Float16* Mp  = (_Float16*)(ws + (size_t)16 * 1024 * 1024);     // 8MB x nsplit

    const size_t MB = (size_t)1024 * 1024;
    int nsplit = 1;
    if      (ws_size >= 48 * MB) nsplit = 4;   // 16 + 4*8 = 48MB
    else if (ws_size >= 32 * MB) nsplit = 2;

    k_prep<<<8192, 256, 0, stream>>>(x, W, x_h, Wt);

    dim3 gg(NCOL / BN, B_ROWS / BM, nsplit);  // 16 x 16 x nsplit
    k_gemm<<<gg, 256, 0, stream>>>(x_h, Wt, Mp, (FEAT / BK) / nsplit);

    k_pairwise<<<B_ROWS, 256, 0, stream>>>(Mp, nsplit, Os);
}

// Round 6
// 67.147 us; speedup vs baseline: 1.3472x; 1.1128x over previous
//
#include <hip/hip_runtime.h>
#include <hip/hip_bf16.h>
#include <hip/hip_fp16.h>
#include <stdint.h>

#define B_ROWS 2048
#define FEAT   2048
#define NK     128
#define ND     16
#define NCOL   2048   // NK*ND

#define BM 128
#define BN 128
#define BK 64

typedef __attribute__((ext_vector_type(4))) float    f32x4;
typedef __attribute__((ext_vector_type(8)))  _Float16 f16x8;
typedef __attribute__((ext_vector_type(4)))  _Float16 f16x4;
typedef __attribute__((ext_vector_type(2)))  _Float16 f16x2;

__device__ __forceinline__ f16x2 u2h(unsigned u) { return __builtin_bit_cast(f16x2, u); }
__device__ __forceinline__ f16x2 absdiff2(f16x2 a, f16x2 b) {
    f16x2 d = a - b;                       // v_pk_sub_f16
    unsigned u = __builtin_bit_cast(unsigned, d) & 0x7fff7fffu;  // v_and_b32 (abs both halves)
    return __builtin_bit_cast(f16x2, u);
}

// ------------- Kernel 1: fused x-convert + W-transpose/convert (f16) ------
__global__ __launch_bounds__(256) void k_prep(const float* __restrict__ x,
                                              const float* __restrict__ W,
                                              _Float16* __restrict__ x_h,
                                              _Float16* __restrict__ Wt) {
    __shared__ float tile[32][33];
    int bb = blockIdx.x;
    if (bb < 4096) {
        int i = bb * 256 + threadIdx.x;
        float4 v = ((const float4*)x)[i];
        f16x4 o = { (_Float16)v.x, (_Float16)v.y, (_Float16)v.z, (_Float16)v.w };
        *(f16x4*)&x_h[(size_t)i * 4] = o;
    } else {
        bb -= 4096;
        int tid = threadIdx.x;
        int tx = tid & 31, ty = tid >> 5;   // 32 x 8
        int n0 = (bb & 63) * 32, k0 = (bb >> 6) * 32;
        #pragma unroll
        for (int i = 0; i < 4; ++i)
            tile[ty + i * 8][tx] = W[(size_t)(k0 + ty + i * 8) * NCOL + n0 + tx];
        __syncthreads();
        #pragma unroll
        for (int i = 0; i < 4; ++i)
            Wt[(size_t)(n0 + ty + i * 8) * FEAT + k0 + tx] = (_Float16)tile[tx][ty + i * 8];
    }
}

// ---------------- Kernel 2: f16 MFMA GEMM, 2-phase double-buffered --------
// T3-minimum pipeline: STAGE(next buf) issued BEFORE compute(cur buf); raw
// s_barrier + counted s_waitcnt vmcnt(8) so next-tile loads stay in flight
// across the barrier (never drain to 0 mid-loop). LDS 64KB -> 2 blocks/CU.
__global__ __launch_bounds__(256) void k_gemm(const _Float16* __restrict__ A,
                                              const _Float16* __restrict__ Bt,
                                              _Float16* __restrict__ Cparts,
                                              int kt_per) {
    __shared__ __align__(16) unsigned short As[2][BM * BK];  // 2 x 16KB
    __shared__ __align__(16) unsigned short Bs[2][BN * BK];  // 2 x 16KB
    const int tid  = threadIdx.x;
    const int wave = tid >> 6;
    const int lane = tid & 63;
    const int bm = blockIdx.y, bn = blockIdx.x, z = blockIdx.z;
    _Float16* C = Cparts + (size_t)z * B_ROWS * NCOL;
    const int wm = (wave >> 1) * 64;
    const int wn = (wave & 1) * 64;

    const int srow  = lane >> 3;
    const int skcol = (lane & 7) * 8;

    // Per-thread staging sources: 4 chunks x (A,B) = 8 global_load_lds/stage
    const int mrow_s = wave * 32 + srow;                 // + r*8
    const _Float16* gA0 = A  + (size_t)(bm * BM + mrow_s) * FEAT + skcol;
    const _Float16* gB0 = Bt + (size_t)(bn * BN + mrow_s) * FEAT + skcol;
    const int lofs = (wave * 4) * 512 + (srow * 64 + (skcol & 63)) - (srow * 64 + skcol - srow * 64 - skcol); // = base chunk offset helper (kept simple below)

    f32x4 acc[4][4];
    #pragma unroll
    for (int i = 0; i < 4; ++i)
        #pragma unroll
        for (int j = 0; j < 4; ++j)
            acc[i][j] = (f32x4){0.f, 0.f, 0.f, 0.f};

    const int fr = lane & 15;
    const int fk = (lane >> 4) * 8;

    const int kt0   = z * kt_per;
    const int ktEnd = kt0 + kt_per;

#define STAGE(buf, k0)                                                                  \
    {                                                                                   \
        _Pragma("unroll")                                                               \
        for (int r = 0; r < 4; ++r) {                                                   \
            const _Float16* ga = gA0 + (size_t)(r * 8) * FEAT + (k0);                   \
            const _Float16* gb = gB0 + (size_t)(r * 8) * FEAT + (k0);                   \
            unsigned short* la = &As[buf][(wave * 4 + r) * 512 + srow * 64 + skcol];    \
            unsigned short* lb = &Bs[buf][(wave * 4 + r) * 512 + srow * 64 + skcol];    \
            __builtin_amdgcn_global_load_lds((const __attribute__((address_space(1))) uint32_t*)ga, \
                                             (__attribute__((address_space(3))) uint32_t*)la, 16, 0, 0); \
            __builtin_amdgcn_global_load_lds((const __attribute__((address_space(1))) uint32_t*)gb, \
                                             (__attribute__((address_space(3))) uint32_t*)lb, 16, 0, 0); \
        }                                                                               \
    }

    STAGE(0, kt0 * BK);
    for (int kt = kt0; kt < ktEnd; ++kt) {
        const int cur = (kt - kt0) & 1;
        if (kt + 1 < ktEnd) {
            STAGE(cur ^ 1, (kt + 1) * BK);
            asm volatile("s_waitcnt vmcnt(8)" ::: "memory");  // oldest 8 (cur tile) done
        } else {
            asm volatile("s_waitcnt vmcnt(0)" ::: "memory");
        }
        __builtin_amdgcn_s_barrier();   // all threads' cur tile in LDS; next stays in flight

        #pragma unroll
        for (int kk = 0; kk < BK; kk += 32) {
            f16x8 av[4], bv[4];
            #pragma unroll
            for (int t = 0; t < 4; ++t)
                av[t] = *(const f16x8*)&As[cur][(wm + t * 16 + fr) * BK + kk + fk];
            #pragma unroll
            for (int t = 0; t < 4; ++t)
                bv[t] = *(const f16x8*)&Bs[cur][(wn + t * 16 + fr) * BK + kk + fk];
            #pragma unroll
            for (int i = 0; i < 4; ++i)
                #pragma unroll
                for (int j = 0; j < 4; ++j)
                    acc[i][j] = __builtin_amdgcn_mfma_f32_16x16x32_f16(av[i], bv[j], acc[i][j], 0, 0, 0);
        }
        __builtin_amdgcn_s_barrier();   // compute(cur) done before cur is re-staged
    }
#undef STAGE

    const int crow0 = bm * BM + wm + (lane >> 4) * 4;
    const int ccol0 = bn * BN + wn + (lane & 15);
    #pragma unroll
    for (int i = 0; i < 4; ++i)
        #pragma unroll
        for (int j = 0; j < 4; ++j)
            #pragma unroll
            for (int r = 0; r < 4; ++r)
                C[(size_t)(crow0 + i * 16 + r) * NCOL + ccol0 + j * 16] = (_Float16)acc[i][j][r];
}

// ---------------- Kernel 3: pairwise L1 + exp2 (clean packed-f16) ---------
// One batch row per block (2048 blocks, 8/CU -> 32 waves/CU). Unchanged R5.
__global__ __launch_bounds__(256) void k_pairwise(const _Float16* __restrict__ Mp,
                                                  int nparts,
                                                  float* __restrict__ Os) {
    __shared__ _Float16 rowl[NCOL];        // 4KB
    __shared__ float    part[2][NK];       // 1KB
    const int b  = blockIdx.x;
    const int t  = threadIdx.x;
    const int i  = t & 127;
    const int jh = t >> 7;                 // wave-uniform (waves 0,1 / 2,3)

    const size_t PART  = (size_t)B_ROWS * NCOL;
    const size_t gbase = (size_t)b * NCOL;
    const f16x2 lg2e = { (_Float16)1.44269504f, (_Float16)1.44269504f };

    // Stage: each thread one f16x8 chunk; sum split-K partials; scale.
    {
        f16x8 v = *(const f16x8*)(Mp + gbase + (size_t)t * 8);
        for (int z = 1; z < nparts; ++z)
            v = v + *(const f16x8*)(Mp + (size_t)z * PART + gbase + (size_t)t * 8);
        f16x2 a0 = { v[0], v[1] }, a1 = { v[2], v[3] }, a2 = { v[4], v[5] }, a3 = { v[6], v[7] };
        a0 *= lg2e; a1 *= lg2e; a2 *= lg2e; a3 *= lg2e;
        uint4 w = { __builtin_bit_cast(unsigned, a0), __builtin_bit_cast(unsigned, a1),
                    __builtin_bit_cast(unsigned, a2), __builtin_bit_cast(unsigned, a3) };
        *(uint4*)&rowl[t * 8] = w;
    }
    __syncthreads();

    const uint4 ua = *(const uint4*)&rowl[i * ND];
    const uint4 ub = *(const uint4*)&rowl[i * ND + 8];
    const f16x2 m0 = u2h(ua.x), m1 = u2h(ua.y), m2 = u2h(ua.z), m3 = u2h(ua.w);
    const f16x2 m4 = u2h(ub.x), m5 = u2h(ub.y), m6 = u2h(ub.z), m7 = u2h(ub.w);

    float acc0 = 0.f, acc1 = 0.f;
    const _Float16* jp = rowl + jh * 64 * ND;
    #pragma unroll 2
    for (int jj = 0; jj < 64; ++jj) {
        const uint4 va = *(const uint4*)(jp + jj * ND);      // wave-uniform broadcast
        const uint4 vb = *(const uint4*)(jp + jj * ND + 8);
        f16x2 s0 = absdiff2(m0, u2h(va.x)) + absdiff2(m1, u2h(va.y));
        f16x2 s1 = absdiff2(m2, u2h(va.z)) + absdiff2(m3, u2h(va.w));
        f16x2 s2 = absdiff2(m4, u2h(vb.x)) + absdiff2(m5, u2h(vb.y));
        f16x2 s3 = absdiff2(m6, u2h(vb.z)) + absdiff2(m7, u2h(vb.w));
        f16x2 s01 = s0 + s1, s23 = s2 + s3;
        f16x2 s = s01 + s23;
        _Float16 nh = s[0] + s[1];             // v_add_f16
        float nrm = (float)nh;                 // v_cvt_f32_f16
        if (jj & 1) acc1 += __builtin_amdgcn_exp2f(-nrm);
        else        acc0 += __builtin_amdgcn_exp2f(-nrm);
    }
    part[jh][i] = acc0 + acc1;
    __syncthreads();
    if (t < NK) Os[(size_t)b * NK + t] = part[0][t] + part[1][t];
}

extern "C" void kernel_launch(void* const* d_in, const int* in_sizes, int n_in,
                              void* d_out, int out_size, void* d_ws, size_t ws_size,
                              hipStream_t stream) {
    const float* x = (const float*)d_in[0];
    const float* W = (const float*)d_in[1];
    float* Os = (float*)d_out;

    char* ws = (char*)d_ws;
    _Float16* x_h = (_Float16*)ws;                                  // 8MB
    _Float16* Wt  = (_Float16*)(ws + (size_t)8  * 1024 * 1024);     // 8MB
    _Float16* Mp  = (_Float16*)(ws + (size_t)16 * 1024 * 1024);     // 8MB x nsplit

    const size_t MB = (size_t)1024 * 1024;
    const int nsplit = (ws_size >= 32 * MB) ? 2 : 1;   // 512 blocks = 2/CU, one pass

    k_prep<<<8192, 256, 0, stream>>>(x, W, x_h, Wt);

    dim3 gg(NCOL / BN, B_ROWS / BM, nsplit);  // 16 x 16 x nsplit
    k_gemm<<<gg, 256, 0, stream>>>(x_h, Wt, Mp, (FEAT / BK) / nsplit);

    k_pairwise<<<B_ROWS, 256, 0, stream>>>(Mp, nsplit, Os);
}

// Round 7
// 66.348 us; speedup vs baseline: 1.3634x; 1.0120x over previous
//
#include <hip/hip_runtime.h>
#include <hip/hip_bf16.h>
#include <hip/hip_fp16.h>
#include <stdint.h>

#define B_ROWS 2048
#define FEAT   2048
#define NK     128
#define ND     16
#define NCOL   2048   // NK*ND

#define BM 128
#define BN 128
#define BK 64

typedef __attribute__((ext_vector_type(4))) float    f32x4;
typedef __attribute__((ext_vector_type(8)))  _Float16 f16x8;
typedef __attribute__((ext_vector_type(4)))  _Float16 f16x4;
typedef __attribute__((ext_vector_type(2)))  _Float16 f16x2;

__device__ __forceinline__ f16x2 u2h(unsigned u) { return __builtin_bit_cast(f16x2, u); }
__device__ __forceinline__ f16x2 absdiff2(f16x2 a, f16x2 b) {
    f16x2 d = a - b;                       // v_pk_sub_f16
    unsigned u = __builtin_bit_cast(unsigned, d) & 0x7fff7fffu;  // v_and_b32 (abs both halves)
    return __builtin_bit_cast(f16x2, u);
}

// ------------- Kernel 1: fused x-convert + W-transpose/convert (f16) ------
__global__ __launch_bounds__(256) void k_prep(const float* __restrict__ x,
                                              const float* __restrict__ W,
                                              _Float16* __restrict__ x_h,
                                              _Float16* __restrict__ Wt) {
    __shared__ float tile[32][33];
    int bb = blockIdx.x;
    if (bb < 4096) {
        int i = bb * 256 + threadIdx.x;
        float4 v = ((const float4*)x)[i];
        f16x4 o = { (_Float16)v.x, (_Float16)v.y, (_Float16)v.z, (_Float16)v.w };
        *(f16x4*)&x_h[(size_t)i * 4] = o;
    } else {
        bb -= 4096;
        int tid = threadIdx.x;
        int tx = tid & 31, ty = tid >> 5;   // 32 x 8
        int n0 = (bb & 63) * 32, k0 = (bb >> 6) * 32;
        #pragma unroll
        for (int i = 0; i < 4; ++i)
            tile[ty + i * 8][tx] = W[(size_t)(k0 + ty + i * 8) * NCOL + n0 + tx];
        __syncthreads();
        #pragma unroll
        for (int i = 0; i < 4; ++i)
            Wt[(size_t)(n0 + ty + i * 8) * FEAT + k0 + tx] = (_Float16)tile[tx][ty + i * 8];
    }
}

// ---------------- Kernel 2: f16 MFMA GEMM, 2-phase double-buffered --------
// Unchanged from R6 (T3-minimum pipeline, counted vmcnt(8), 64KB LDS).
__global__ __launch_bounds__(256) void k_gemm(const _Float16* __restrict__ A,
                                              const _Float16* __restrict__ Bt,
                                              _Float16* __restrict__ Cparts,
                                              int kt_per) {
    __shared__ __align__(16) unsigned short As[2][BM * BK];  // 2 x 16KB
    __shared__ __align__(16) unsigned short Bs[2][BN * BK];  // 2 x 16KB
    const int tid  = threadIdx.x;
    const int wave = tid >> 6;
    const int lane = tid & 63;
    const int bm = blockIdx.y, bn = blockIdx.x, z = blockIdx.z;
    _Float16* C = Cparts + (size_t)z * B_ROWS * NCOL;
    const int wm = (wave >> 1) * 64;
    const int wn = (wave & 1) * 64;

    const int srow  = lane >> 3;
    const int skcol = (lane & 7) * 8;

    const int mrow_s = wave * 32 + srow;                 // + r*8
    const _Float16* gA0 = A  + (size_t)(bm * BM + mrow_s) * FEAT + skcol;
    const _Float16* gB0 = Bt + (size_t)(bn * BN + mrow_s) * FEAT + skcol;

    f32x4 acc[4][4];
    #pragma unroll
    for (int i = 0; i < 4; ++i)
        #pragma unroll
        for (int j = 0; j < 4; ++j)
            acc[i][j] = (f32x4){0.f, 0.f, 0.f, 0.f};

    const int fr = lane & 15;
    const int fk = (lane >> 4) * 8;

    const int kt0   = z * kt_per;
    const int ktEnd = kt0 + kt_per;

#define STAGE(buf, k0)                                                                  \
    {                                                                                   \
        _Pragma("unroll")                                                               \
        for (int r = 0; r < 4; ++r) {                                                   \
            const _Float16* ga = gA0 + (size_t)(r * 8) * FEAT + (k0);                   \
            const _Float16* gb = gB0 + (size_t)(r * 8) * FEAT + (k0);                   \
            unsigned short* la = &As[buf][(wave * 4 + r) * 512 + srow * 64 + skcol];    \
            unsigned short* lb = &Bs[buf][(wave * 4 + r) * 512 + srow * 64 + skcol];    \
            __builtin_amdgcn_global_load_lds((const __attribute__((address_space(1))) uint32_t*)ga, \
                                             (__attribute__((address_space(3))) uint32_t*)la, 16, 0, 0); \
            __builtin_amdgcn_global_load_lds((const __attribute__((address_space(1))) uint32_t*)gb, \
                                             (__attribute__((address_space(3))) uint32_t*)lb, 16, 0, 0); \
        }                                                                               \
    }

    STAGE(0, kt0 * BK);
    for (int kt = kt0; kt < ktEnd; ++kt) {
        const int cur = (kt - kt0) & 1;
        if (kt + 1 < ktEnd) {
            STAGE(cur ^ 1, (kt + 1) * BK);
            asm volatile("s_waitcnt vmcnt(8)" ::: "memory");  // oldest 8 (cur tile) done
        } else {
            asm volatile("s_waitcnt vmcnt(0)" ::: "memory");
        }
        __builtin_amdgcn_s_barrier();   // cur tile in LDS; next stays in flight

        #pragma unroll
        for (int kk = 0; kk < BK; kk += 32) {
            f16x8 av[4], bv[4];
            #pragma unroll
            for (int t = 0; t < 4; ++t)
                av[t] = *(const f16x8*)&As[cur][(wm + t * 16 + fr) * BK + kk + fk];
            #pragma unroll
            for (int t = 0; t < 4; ++t)
                bv[t] = *(const f16x8*)&Bs[cur][(wn + t * 16 + fr) * BK + kk + fk];
            #pragma unroll
            for (int i = 0; i < 4; ++i)
                #pragma unroll
                for (int j = 0; j < 4; ++j)
                    acc[i][j] = __builtin_amdgcn_mfma_f32_16x16x32_f16(av[i], bv[j], acc[i][j], 0, 0, 0);
        }
        __builtin_amdgcn_s_barrier();   // compute(cur) done before cur re-staged
    }
#undef STAGE

    const int crow0 = bm * BM + wm + (lane >> 4) * 4;
    const int ccol0 = bn * BN + wn + (lane & 15);
    #pragma unroll
    for (int i = 0; i < 4; ++i)
        #pragma unroll
        for (int j = 0; j < 4; ++j)
            #pragma unroll
            for (int r = 0; r < 4; ++r)
                C[(size_t)(crow0 + i * 16 + r) * NCOL + ccol0 + j * 16] = (_Float16)acc[i][j][r];
}

// ---------------- Kernel 3: pairwise L1 + exp2, TI=2 x jsplit=8 -----------
// One batch row per block, 512 threads = 8 waves. Wave w owns j-chunk
// [w*16, w*16+16); lane tl owns outputs i=tl and i=tl+64 (all 128 i's in
// ONE wave -> each (row,j) vj-row read exactly once per wave: LDS return
// traffic halved vs R5/R6). Named-register packed-f16 math throughout.
#define JW 8
__global__ __launch_bounds__(512) void k_pairwise(const _Float16* __restrict__ Mp,
                                                  int nparts,
                                                  float* __restrict__ Os) {
    __shared__ _Float16 rowl[NCOL];        // 4KB
    __shared__ float    part[JW][NK];      // 4KB
    const int b  = blockIdx.x;
    const int t  = threadIdx.x;
    const int w  = t >> 6;                 // wave id = j-group (wave-uniform)
    const int tl = t & 63;                 // lane: owns i = tl, tl+64

    const size_t PART  = (size_t)B_ROWS * NCOL;
    const size_t gbase = (size_t)b * NCOL;
    const f16x2 lg2e = { (_Float16)1.44269504f, (_Float16)1.44269504f };

    // Stage: threads 0..255 load one f16x8 chunk; sum split-K partials; scale.
    if (t < 256) {
        f16x8 v = *(const f16x8*)(Mp + gbase + (size_t)t * 8);
        for (int z = 1; z < nparts; ++z)
            v = v + *(const f16x8*)(Mp + (size_t)z * PART + gbase + (size_t)t * 8);
        f16x2 a0 = { v[0], v[1] }, a1 = { v[2], v[3] }, a2 = { v[4], v[5] }, a3 = { v[6], v[7] };
        a0 *= lg2e; a1 *= lg2e; a2 *= lg2e; a3 *= lg2e;
        uint4 wr = { __builtin_bit_cast(unsigned, a0), __builtin_bit_cast(unsigned, a1),
                     __builtin_bit_cast(unsigned, a2), __builtin_bit_cast(unsigned, a3) };
        *(uint4*)&rowl[t * 8] = wr;
    }
    __syncthreads();

    // Own-row fragments for i=tl (ma*) and i=tl+64 (mb*): 16 named f16x2.
    const uint4 uaA = *(const uint4*)&rowl[tl * ND];
    const uint4 uaB = *(const uint4*)&rowl[tl * ND + 8];
    const uint4 ubA = *(const uint4*)&rowl[(tl + 64) * ND];
    const uint4 ubB = *(const uint4*)&rowl[(tl + 64) * ND + 8];
    const f16x2 ma0 = u2h(uaA.x), ma1 = u2h(uaA.y), ma2 = u2h(uaA.z), ma3 = u2h(uaA.w);
    const f16x2 ma4 = u2h(uaB.x), ma5 = u2h(uaB.y), ma6 = u2h(uaB.z), ma7 = u2h(uaB.w);
    const f16x2 mb0 = u2h(ubA.x), mb1 = u2h(ubA.y), mb2 = u2h(ubA.z), mb3 = u2h(ubA.w);
    const f16x2 mb4 = u2h(ubB.x), mb5 = u2h(ubB.y), mb6 = u2h(ubB.z), mb7 = u2h(ubB.w);

    float accA0 = 0.f, accA1 = 0.f, accB0 = 0.f, accB1 = 0.f;
    const _Float16* jp = rowl + w * 16 * ND;
    #pragma unroll 4
    for (int jj = 0; jj < 16; ++jj) {
        const uint4 va = *(const uint4*)(jp + jj * ND);      // wave-uniform broadcast
        const uint4 vb = *(const uint4*)(jp + jj * ND + 8);
        const f16x2 v0 = u2h(va.x), v1 = u2h(va.y), v2 = u2h(va.z), v3 = u2h(va.w);
        const f16x2 v4 = u2h(vb.x), v5 = u2h(vb.y), v6 = u2h(vb.z), v7 = u2h(vb.w);
        {
            f16x2 s01 = (absdiff2(ma0, v0) + absdiff2(ma1, v1))
                      + (absdiff2(ma2, v2) + absdiff2(ma3, v3));
            f16x2 s23 = (absdiff2(ma4, v4) + absdiff2(ma5, v5))
                      + (absdiff2(ma6, v6) + absdiff2(ma7, v7));
            f16x2 s = s01 + s23;
            float nrm = (float)(_Float16)(s[0] + s[1]);
            if (jj & 1) accA1 += __builtin_amdgcn_exp2f(-nrm);
            else        accA0 += __builtin_amdgcn_exp2f(-nrm);
        }
        {
            f16x2 s01 = (absdiff2(mb0, v0) + absdiff2(mb1, v1))
                      + (absdiff2(mb2, v2) + absdiff2(mb3, v3));
            f16x2 s23 = (absdiff2(mb4, v4) + absdiff2(mb5, v5))
                      + (absdiff2(mb6, v6) + absdiff2(mb7, v7));
            f16x2 s = s01 + s23;
            float nrm = (float)(_Float16)(s[0] + s[1]);
            if (jj & 1) accB1 += __builtin_amdgcn_exp2f(-nrm);
            else        accB0 += __builtin_amdgcn_exp2f(-nrm);
        }
    }
    part[w][tl]      = accA0 + accA1;
    part[w][tl + 64] = accB0 + accB1;
    __syncthreads();
    if (t < NK) {
        float s0 = (part[0][t] + part[1][t]) + (part[2][t] + part[3][t]);
        float s1 = (part[4][t] + part[5][t]) + (part[6][t] + part[7][t]);
        Os[(size_t)b * NK + t] = s0 + s1;
    }
}

extern "C" void kernel_launch(void* const* d_in, const int* in_sizes, int n_in,
                              void* d_out, int out_size, void* d_ws, size_t ws_size,
                              hipStream_t stream) {
    const float* x = (const float*)d_in[0];
    const float* W = (const float*)d_in[1];
    float* Os = (float*)d_out;

    char* ws = (char*)d_ws;
    _Float16* x_h = (_Float16*)ws;                                  // 8MB
    _Float16* Wt  = (_Float16*)(ws + (size_t)8  * 1024 * 1024);     // 8MB
    _Float16* Mp  = (_Float16*)(ws + (size_t)16 * 1024 * 1024);     // 8MB x nsplit

    const size_t MB = (size_t)1024 * 1024;
    const int nsplit = (ws_size >= 32 * MB) ? 2 : 1;   // 512 blocks = 2/CU, one pass

    k_prep<<<8192, 256, 0, stream>>>(x, W, x_h, Wt);

    dim3 gg(NCOL / BN, B_ROWS / BM, nsplit);  // 16 x 16 x nsplit
    k_gemm<<<gg, 256, 0, stream>>>(x_h, Wt, Mp, (FEAT / BK) / nsplit);

    k_pairwise<<<B_ROWS, 512, 0, stream>>>(Mp, nsplit, Os);
}

// Round 8
// 58.413 us; speedup vs baseline: 1.5486x; 1.1358x over previous
//
#include <hip/hip_runtime.h>
#include <hip/hip_bf16.h>
#include <hip/hip_fp16.h>
#include <stdint.h>

#define B_ROWS 2048
#define FEAT   2048
#define NK     128
#define ND     16
#define NCOL   2048   // NK*ND

#define BM 128
#define BN 128
#define BK 64

typedef __attribute__((ext_vector_type(4))) float    f32x4;
typedef __attribute__((ext_vector_type(8)))  _Float16 f16x8;
typedef __attribute__((ext_vector_type(4)))  _Float16 f16x4;
typedef __attribute__((ext_vector_type(2)))  _Float16 f16x2;

__device__ __forceinline__ f16x2 u2h(unsigned u) { return __builtin_bit_cast(f16x2, u); }
__device__ __forceinline__ f16x2 absdiff2(f16x2 a, f16x2 b) {
    f16x2 d = a - b;                       // v_pk_sub_f16
    unsigned u = __builtin_bit_cast(unsigned, d) & 0x7fff7fffu;  // v_and_b32 (abs both halves)
    return __builtin_bit_cast(f16x2, u);
}

// ------------- Kernel 1: fused x-convert + W-transpose/convert (f16) ------
__global__ __launch_bounds__(256) void k_prep(const float* __restrict__ x,
                                              const float* __restrict__ W,
                                              _Float16* __restrict__ x_h,
                                              _Float16* __restrict__ Wt) {
    __shared__ float tile[32][33];
    int bb = blockIdx.x;
    if (bb < 4096) {
        int i = bb * 256 + threadIdx.x;
        float4 v = ((const float4*)x)[i];
        f16x4 o = { (_Float16)v.x, (_Float16)v.y, (_Float16)v.z, (_Float16)v.w };
        *(f16x4*)&x_h[(size_t)i * 4] = o;
    } else {
        bb -= 4096;
        int tid = threadIdx.x;
        int tx = tid & 31, ty = tid >> 5;   // 32 x 8
        int n0 = (bb & 63) * 32, k0 = (bb >> 6) * 32;
        #pragma unroll
        for (int i = 0; i < 4; ++i)
            tile[ty + i * 8][tx] = W[(size_t)(k0 + ty + i * 8) * NCOL + n0 + tx];
        __syncthreads();
        #pragma unroll
        for (int i = 0; i < 4; ++i)
            Wt[(size_t)(n0 + ty + i * 8) * FEAT + k0 + tx] = (_Float16)tile[tx][ty + i * 8];
    }
}

// ---------------- Kernel 2: f16 MFMA GEMM, 2-phase double-buffered --------
// Unchanged from R6/R7 (T3-minimum pipeline, counted vmcnt(8), 64KB LDS).
__global__ __launch_bounds__(256) void k_gemm(const _Float16* __restrict__ A,
                                              const _Float16* __restrict__ Bt,
                                              _Float16* __restrict__ Cparts,
                                              int kt_per) {
    __shared__ __align__(16) unsigned short As[2][BM * BK];  // 2 x 16KB
    __shared__ __align__(16) unsigned short Bs[2][BN * BK];  // 2 x 16KB
    const int tid  = threadIdx.x;
    const int wave = tid >> 6;
    const int lane = tid & 63;
    const int bm = blockIdx.y, bn = blockIdx.x, z = blockIdx.z;
    _Float16* C = Cparts + (size_t)z * B_ROWS * NCOL;
    const int wm = (wave >> 1) * 64;
    const int wn = (wave & 1) * 64;

    const int srow  = lane >> 3;
    const int skcol = (lane & 7) * 8;

    const int mrow_s = wave * 32 + srow;                 // + r*8
    const _Float16* gA0 = A  + (size_t)(bm * BM + mrow_s) * FEAT + skcol;
    const _Float16* gB0 = Bt + (size_t)(bn * BN + mrow_s) * FEAT + skcol;

    f32x4 acc[4][4];
    #pragma unroll
    for (int i = 0; i < 4; ++i)
        #pragma unroll
        for (int j = 0; j < 4; ++j)
            acc[i][j] = (f32x4){0.f, 0.f, 0.f, 0.f};

    const int fr = lane & 15;
    const int fk = (lane >> 4) * 8;

    const int kt0   = z * kt_per;
    const int ktEnd = kt0 + kt_per;

#define STAGE(buf, k0)                                                                  \
    {                                                                                   \
        _Pragma("unroll")                                                               \
        for (int r = 0; r < 4; ++r) {                                                   \
            const _Float16* ga = gA0 + (size_t)(r * 8) * FEAT + (k0);                   \
            const _Float16* gb = gB0 + (size_t)(r * 8) * FEAT + (k0);                   \
            unsigned short* la = &As[buf][(wave * 4 + r) * 512 + srow * 64 + skcol];    \
            unsigned short* lb = &Bs[buf][(wave * 4 + r) * 512 + srow * 64 + skcol];    \
            __builtin_amdgcn_global_load_lds((const __attribute__((address_space(1))) uint32_t*)ga, \
                                             (__attribute__((address_space(3))) uint32_t*)la, 16, 0, 0); \
            __builtin_amdgcn_global_load_lds((const __attribute__((address_space(1))) uint32_t*)gb, \
                                             (__attribute__((address_space(3))) uint32_t*)lb, 16, 0, 0); \
        }                                                                               \
    }

    STAGE(0, kt0 * BK);
    for (int kt = kt0; kt < ktEnd; ++kt) {
        const int cur = (kt - kt0) & 1;
        if (kt + 1 < ktEnd) {
            STAGE(cur ^ 1, (kt + 1) * BK);
            asm volatile("s_waitcnt vmcnt(8)" ::: "memory");  // oldest 8 (cur tile) done
        } else {
            asm volatile("s_waitcnt vmcnt(0)" ::: "memory");
        }
        __builtin_amdgcn_s_barrier();   // cur tile in LDS; next stays in flight

        #pragma unroll
        for (int kk = 0; kk < BK; kk += 32) {
            f16x8 av[4], bv[4];
            #pragma unroll
            for (int t = 0; t < 4; ++t)
                av[t] = *(const f16x8*)&As[cur][(wm + t * 16 + fr) * BK + kk + fk];
            #pragma unroll
            for (int t = 0; t < 4; ++t)
                bv[t] = *(const f16x8*)&Bs[cur][(wn + t * 16 + fr) * BK + kk + fk];
            #pragma unroll
            for (int i = 0; i < 4; ++i)
                #pragma unroll
                for (int j = 0; j < 4; ++j)
                    acc[i][j] = __builtin_amdgcn_mfma_f32_16x16x32_f16(av[i], bv[j], acc[i][j], 0, 0, 0);
        }
        __builtin_amdgcn_s_barrier();   // compute(cur) done before cur re-staged
    }
#undef STAGE

    const int crow0 = bm * BM + wm + (lane >> 4) * 4;
    const int ccol0 = bn * BN + wn + (lane & 15);
    #pragma unroll
    for (int i = 0; i < 4; ++i)
        #pragma unroll
        for (int j = 0; j < 4; ++j)
            #pragma unroll
            for (int r = 0; r < 4; ++r)
                C[(size_t)(crow0 + i * 16 + r) * NCOL + ccol0 + j * 16] = (_Float16)acc[i][j][r];
}

// ------- Kernel 3: pairwise L1+exp2, SYMMETRIC (each pair computed once) --
// Block = 1 batch row, 256 threads = 4 waves, 8 blocks/CU (32 waves/CU).
// Lane tl owns i0=tl, i1=tl+64. Wave w handles offsets o in [w*16+1, w*16+16].
// For o<64: lane computes e(i0,(i0+o)&127) and e(i1,(i1+o)&127) -- every
// unordered pair exactly once across the block -- self-accumulates, and
// ships both values to receiver lane (tl+o)&63 via __shfl; receiver swaps
// acc0/acc1 iff wrapped (rl < o). o==64 is the {tl,tl+64} pair, credited to
// both accs. Diagonal = exact +1.0 at the end.
#define JWAVES 4
__global__ __launch_bounds__(256, 8) void k_pairwise(const _Float16* __restrict__ Mp,
                                                     int nparts,
                                                     float* __restrict__ Os) {
    __shared__ _Float16 rowl[NCOL];          // 4KB (one row, lg2e-prescaled)
    __shared__ float    part[JWAVES][2][64]; // 2KB
    const int b  = blockIdx.x;
    const int t  = threadIdx.x;
    const int w  = t >> 6;                   // wave id (o-chunk)
    const int tl = t & 63;

    const size_t PART  = (size_t)B_ROWS * NCOL;
    const size_t gbase = (size_t)b * NCOL;
    const f16x2 lg2e = { (_Float16)1.44269504f, (_Float16)1.44269504f };

    // Stage: 256 threads x 8 f16; sum split-K partials; prescale by log2(e).
    {
        f16x8 v = *(const f16x8*)(Mp + gbase + (size_t)t * 8);
        for (int z = 1; z < nparts; ++z)
            v = v + *(const f16x8*)(Mp + (size_t)z * PART + gbase + (size_t)t * 8);
        f16x2 a0 = { v[0], v[1] }, a1 = { v[2], v[3] }, a2 = { v[4], v[5] }, a3 = { v[6], v[7] };
        a0 *= lg2e; a1 *= lg2e; a2 *= lg2e; a3 *= lg2e;
        uint4 wr = { __builtin_bit_cast(unsigned, a0), __builtin_bit_cast(unsigned, a1),
                     __builtin_bit_cast(unsigned, a2), __builtin_bit_cast(unsigned, a3) };
        *(uint4*)&rowl[t * 8] = wr;
    }
    __syncthreads();

    // Own fragments: i0=tl (ma*), i1=tl+64 (mb*)
    const uint4 uaA = *(const uint4*)&rowl[tl * ND];
    const uint4 uaB = *(const uint4*)&rowl[tl * ND + 8];
    const uint4 ubA = *(const uint4*)&rowl[(tl + 64) * ND];
    const uint4 ubB = *(const uint4*)&rowl[(tl + 64) * ND + 8];
    const f16x2 ma0 = u2h(uaA.x), ma1 = u2h(uaA.y), ma2 = u2h(uaA.z), ma3 = u2h(uaA.w);
    const f16x2 ma4 = u2h(uaB.x), ma5 = u2h(uaB.y), ma6 = u2h(uaB.z), ma7 = u2h(uaB.w);
    const f16x2 mb0 = u2h(ubA.x), mb1 = u2h(ubA.y), mb2 = u2h(ubA.z), mb3 = u2h(ubA.w);
    const f16x2 mb4 = u2h(ubB.x), mb5 = u2h(ubB.y), mb6 = u2h(ubB.z), mb7 = u2h(ubB.w);

    float acc0 = 0.f, acc1 = 0.f;
    #pragma unroll 2
    for (int jj = 0; jj < 16; ++jj) {
        const int o  = w * 16 + 1 + jj;          // wave-uniform, 1..64
        const int jA = (tl + o) & 127;
        const int jB = jA ^ 64;
        const uint4 va0 = *(const uint4*)&rowl[jA * ND];
        const uint4 va1 = *(const uint4*)&rowl[jA * ND + 8];
        const uint4 vb0 = *(const uint4*)&rowl[jB * ND];
        const uint4 vb1 = *(const uint4*)&rowl[jB * ND + 8];

        float eA, eB;
        {
            f16x2 s01 = (absdiff2(ma0, u2h(va0.x)) + absdiff2(ma1, u2h(va0.y)))
                      + (absdiff2(ma2, u2h(va0.z)) + absdiff2(ma3, u2h(va0.w)));
            f16x2 s23 = (absdiff2(ma4, u2h(va1.x)) + absdiff2(ma5, u2h(va1.y)))
                      + (absdiff2(ma6, u2h(va1.z)) + absdiff2(ma7, u2h(va1.w)));
            f16x2 s = s01 + s23;
            eA = __builtin_amdgcn_exp2f(-(float)(_Float16)(s[0] + s[1]));
        }
        {
            f16x2 s01 = (absdiff2(mb0, u2h(vb0.x)) + absdiff2(mb1, u2h(vb0.y)))
                      + (absdiff2(mb2, u2h(vb0.z)) + absdiff2(mb3, u2h(vb0.w)));
            f16x2 s23 = (absdiff2(mb4, u2h(vb1.x)) + absdiff2(mb5, u2h(vb1.y)))
                      + (absdiff2(mb6, u2h(vb1.z)) + absdiff2(mb7, u2h(vb1.w)));
            f16x2 s = s01 + s23;
            eB = __builtin_amdgcn_exp2f(-(float)(_Float16)(s[0] + s[1]));
        }

        if (o < 64) {
            const int src = (tl - o) & 63;
            const float eA2 = __shfl(eA, src, 64);
            const float eB2 = __shfl(eB, src, 64);
            const bool wrap = tl < o;            // receiver-side wrap test
            acc0 += eA + (wrap ? eB2 : eA2);
            acc1 += eB + (wrap ? eA2 : eB2);
        } else {                                 // o == 64: pair {tl, tl+64}
            acc0 += eA;
            acc1 += eB;
        }
    }
    part[w][0][tl] = acc0;
    part[w][1][tl] = acc1;
    __syncthreads();
    if (t < NK) {
        const int h = t >> 6, il = t & 63;
        float s = 1.0f                            // exact diagonal term
                + (part[0][h][il] + part[1][h][il])
                + (part[2][h][il] + part[3][h][il]);
        Os[(size_t)b * NK + t] = s;
    }
}

extern "C" void kernel_launch(void* const* d_in, const int* in_sizes, int n_in,
                              void* d_out, int out_size, void* d_ws, size_t ws_size,
                              hipStream_t stream) {
    const float* x = (const float*)d_in[0];
    const float* W = (const float*)d_in[1];
    float* Os = (float*)d_out;

    char* ws = (char*)d_ws;
    _Float16* x_h = (_Float16*)ws;                                  // 8MB
    _Float16* Wt  = (_Float16*)(ws + (size_t)8  * 1024 * 1024);     // 8MB
    _Float16* Mp  = (_Float16*)(ws + (size_t)16 * 1024 * 1024);     // 8MB x nsplit

    const size_t MB = (size_t)1024 * 1024;
    const int nsplit = (ws_size >= 32 * MB) ? 2 : 1;   // 512 blocks = 2/CU, one pass

    k_prep<<<8192, 256, 0, stream>>>(x, W, x_h, Wt);

    dim3 gg(NCOL / BN, B_ROWS / BM, nsplit);  // 16 x 16 x nsplit
    k_gemm<<<gg, 256, 0, stream>>>(x_h, Wt, Mp, (FEAT / BK) / nsplit);

    k_pairwise<<<B_ROWS, 256, 0, stream>>>(Mp, nsplit, Os);
}